// Round 1
// baseline (906.377 us; speedup 1.0000x reference)
//
#include <hip/hip_runtime.h>
#include <math.h>

#define N_    16
#define CIN_  10
#define CB_   16
#define H_    512
#define W_    512
#define HW_   (512*512)
#define EPSF  1e-5f

__device__ __forceinline__ float sgm(float z){ return 1.0f/(1.0f+expf(-z)); }

// ---------------- zero stats ----------------
__global__ void k_zero(double* __restrict__ p, int n){
  for (int i=threadIdx.x; i<n; i+=blockDim.x) p[i]=0.0;
}

// ---------------- finalize BN affine: AB[c]=a, AB[C+c]=b  (y = a*v + b) ----------
__global__ void k_fin(const double* __restrict__ S, const float* __restrict__ g,
                      const float* __restrict__ be, float* __restrict__ AB,
                      int C, double invM){
  int c = threadIdx.x;
  if (c < C){
    double s=0.0,q=0.0;
    for (int n=0;n<N_;++n){ s+=S[(n*C+c)*2]; q+=S[(n*C+c)*2+1]; }
    double mean = s*invM;
    double var  = q*invM - mean*mean;
    float a = g[c]*rsqrtf((float)var + EPSF);
    AB[c]   = a;
    AB[C+c] = be[c] - (float)mean*a;
  }
}

// ---------------- pass 1: conv1 (1x1, 10->16) stats only ----------------
__global__ __launch_bounds__(256) void k_stats1(
    const float* __restrict__ x, const float* __restrict__ w1, const float* __restrict__ b1,
    double* __restrict__ S1)
{
  const int n = blockIdx.y;
  const int base = blockIdx.x*4096;
  const float* xp = x + (size_t)n*CIN_*HW_;
  float sum[CB_], sq[CB_];
#pragma unroll
  for (int c=0;c<CB_;++c){ sum[c]=0.f; sq[c]=0.f; }
#pragma unroll 1
  for (int it=0; it<4; ++it){
    const int p = base + it*1024 + threadIdx.x*4;
    float4 xv[CIN_];
#pragma unroll
    for (int ci=0; ci<CIN_; ++ci)
      xv[ci] = *(const float4*)(xp + (size_t)ci*HW_ + p);
#pragma unroll
    for (int co=0; co<CB_; ++co){
      float bb = b1[co];
      float ox=bb, oy=bb, oz=bb, ow=bb;
#pragma unroll
      for (int ci=0; ci<CIN_; ++ci){
        float w = w1[co*CIN_+ci];
        ox += w*xv[ci].x; oy += w*xv[ci].y; oz += w*xv[ci].z; ow += w*xv[ci].w;
      }
      sum[co] += ox+oy+oz+ow;
      sq[co]  += ox*ox+oy*oy+oz*oz+ow*ow;
    }
  }
  __shared__ float red[4][CB_][2];
  const int lane = threadIdx.x & 63, wid = threadIdx.x >> 6;
#pragma unroll
  for (int c=0;c<CB_;++c){
    float s=sum[c], q=sq[c];
    for (int off=32; off>0; off>>=1){ s += __shfl_down(s,off); q += __shfl_down(q,off); }
    if (lane==0){ red[wid][c][0]=s; red[wid][c][1]=q; }
  }
  __syncthreads();
  if (threadIdx.x < CB_*2){
    int c = threadIdx.x>>1, k = threadIdx.x&1;
    float t = red[0][c][k]+red[1][c][k]+red[2][c][k]+red[3][c][k];
    atomicAdd(&S1[(n*CB_+c)*2+k], (double)t);
  }
}

// ---- pass 2: recompute conv1 -> BN1 -> sigmoid -> conv2 (1x1,16->16); write pre-BN2; stats2 ----
__global__ __launch_bounds__(256) void k_band2(
    const float* __restrict__ x,
    const float* __restrict__ w1, const float* __restrict__ b1, const float* __restrict__ AB1,
    const float* __restrict__ w2, const float* __restrict__ b2,
    float* __restrict__ B, double* __restrict__ S2)
{
  const int n = blockIdx.y;
  const int base = blockIdx.x*4096;
  const float* xp = x + (size_t)n*CIN_*HW_;
  float* bp = B + (size_t)n*CB_*HW_;
  float sum[CB_], sq[CB_];
#pragma unroll
  for (int c=0;c<CB_;++c){ sum[c]=0.f; sq[c]=0.f; }
#pragma unroll 1
  for (int it=0; it<4; ++it){
    const int p = base + it*1024 + threadIdx.x*4;
    float4 xv[CIN_];
#pragma unroll
    for (int ci=0; ci<CIN_; ++ci)
      xv[ci] = *(const float4*)(xp + (size_t)ci*HW_ + p);
    float4 s[CB_];
#pragma unroll
    for (int co=0; co<CB_; ++co){
      float bb = b1[co];
      float ox=bb, oy=bb, oz=bb, ow=bb;
#pragma unroll
      for (int ci=0; ci<CIN_; ++ci){
        float w = w1[co*CIN_+ci];
        ox += w*xv[ci].x; oy += w*xv[ci].y; oz += w*xv[ci].z; ow += w*xv[ci].w;
      }
      const float a = AB1[co], sh = AB1[CB_+co];
      s[co].x = sgm(a*ox+sh); s[co].y = sgm(a*oy+sh);
      s[co].z = sgm(a*oz+sh); s[co].w = sgm(a*ow+sh);
    }
#pragma unroll
    for (int co=0; co<CB_; ++co){
      float bb = b2[co];
      float ox=bb, oy=bb, oz=bb, ow=bb;
#pragma unroll
      for (int ci=0; ci<CB_; ++ci){
        float w = w2[co*CB_+ci];
        ox += w*s[ci].x; oy += w*s[ci].y; oz += w*s[ci].z; ow += w*s[ci].w;
      }
      float4 o; o.x=ox; o.y=oy; o.z=oz; o.w=ow;
      *(float4*)(bp + (size_t)co*HW_ + p) = o;
      sum[co] += ox+oy+oz+ow;
      sq[co]  += ox*ox+oy*oy+oz*oz+ow*ow;
    }
  }
  __shared__ float red[4][CB_][2];
  const int lane = threadIdx.x & 63, wid = threadIdx.x >> 6;
#pragma unroll
  for (int c=0;c<CB_;++c){
    float s=sum[c], q=sq[c];
    for (int off=32; off>0; off>>=1){ s += __shfl_down(s,off); q += __shfl_down(q,off); }
    if (lane==0){ red[wid][c][0]=s; red[wid][c][1]=q; }
  }
  __syncthreads();
  if (threadIdx.x < CB_*2){
    int c = threadIdx.x>>1, k = threadIdx.x&1;
    float t = red[0][c][k]+red[1][c][k]+red[2][c][k]+red[3][c][k];
    atomicAdd(&S2[(n*CB_+c)*2+k], (double)t);
  }
}

// ---- pass 3: BN2 + sigmoid in place; per-(n,c) var stats for top-k ----
__global__ __launch_bounds__(256) void k_bnsig(
    float* __restrict__ B, const float* __restrict__ AB2, double* __restrict__ SV)
{
  const int n = blockIdx.z, c = blockIdx.y;
  const float a = AB2[c], b = AB2[CB_+c];
  float* p = B + ((size_t)(n*CB_+c))*HW_ + blockIdx.x*4096;
  float sum=0.f, sq=0.f;
#pragma unroll 1
  for (int it=0; it<4; ++it){
    float4 v = *(float4*)(p + it*1024 + threadIdx.x*4);
    v.x = sgm(a*v.x+b); v.y = sgm(a*v.y+b); v.z = sgm(a*v.z+b); v.w = sgm(a*v.w+b);
    *(float4*)(p + it*1024 + threadIdx.x*4) = v;
    sum += v.x+v.y+v.z+v.w;
    sq  += v.x*v.x+v.y*v.y+v.z*v.z+v.w*v.w;
  }
  __shared__ float red[4][2];
  const int lane = threadIdx.x & 63, wid = threadIdx.x >> 6;
  for (int off=32; off>0; off>>=1){ sum += __shfl_down(sum,off); sq += __shfl_down(sq,off); }
  if (lane==0){ red[wid][0]=sum; red[wid][1]=sq; }
  __syncthreads();
  if (threadIdx.x < 2){
    int k = threadIdx.x;
    float t = red[0][k]+red[1][k]+red[2][k]+red[3][k];
    atomicAdd(&SV[(n*CB_+c)*2+k], (double)t);
  }
}

// ---- top-3 per-sample channels by unbiased variance (stable ties: lowest idx) ----
__global__ void k_topk(const double* __restrict__ SV, int* __restrict__ IDX){
  __shared__ double var[N_][CB_];
  int t = threadIdx.x;
  if (t < N_*CB_){
    int n=t>>4, c=t&15;
    double s=SV[t*2], q=SV[t*2+1];
    const double M = (double)HW_;
    var[n][c] = (q - s*s/M)/(M-1.0);
  }
  __syncthreads();
  if (t < N_){
    double v[CB_];
#pragma unroll
    for (int c=0;c<CB_;++c) v[c]=var[t][c];
    for (int k=0;k<3;++k){
      int bi=0; double bv=v[0];
#pragma unroll
      for (int c=1;c<CB_;++c) if (v[c]>bv){ bv=v[c]; bi=c; }
      IDX[t*3+k]=bi; v[bi]=-1e300;
    }
  }
}

// ---- conv3x3 (3->8, pad1) + maxpool2 + sigmoid (monotone swap) -> X1[16,8,256,256] ----
__global__ __launch_bounds__(256) void k_conv1p(
    const float* __restrict__ B, const int* __restrict__ IDX,
    const float* __restrict__ w, const float* __restrict__ bias,
    float* __restrict__ X1)
{
  const int n = blockIdx.y, ho = blockIdx.x, wo = threadIdx.x;
  __shared__ int chs[3];
  if (threadIdx.x < 3) chs[threadIdx.x] = IDX[n*3+threadIdx.x];
  __syncthreads();
  float in[3][4][4];
#pragma unroll
  for (int k=0;k<3;++k){
    const float* pc = B + ((size_t)(n*CB_+chs[k]))*HW_;
#pragma unroll
    for (int dy=0;dy<4;++dy){
      int r = 2*ho-1+dy;
      bool rok = (r>=0 && r<H_);
#pragma unroll
      for (int dx=0;dx<4;++dx){
        int cc = 2*wo-1+dx;
        in[k][dy][dx] = (rok && cc>=0 && cc<W_) ? pc[(size_t)r*W_+cc] : 0.f;
      }
    }
  }
#pragma unroll
  for (int co=0;co<8;++co){
    float m = -1e30f;
#pragma unroll
    for (int py=0;py<2;++py)
#pragma unroll
    for (int px=0;px<2;++px){
      float acc = bias[co];
#pragma unroll
      for (int k=0;k<3;++k)
#pragma unroll
      for (int kh=0;kh<3;++kh)
#pragma unroll
      for (int kw=0;kw<3;++kw)
        acc += w[((co*3+k)*3+kh)*3+kw] * in[k][py+kh][px+kw];
      m = fmaxf(m, acc);
    }
    X1[((size_t)(n*8+co)*256 + ho)*256 + wo] = sgm(m);
  }
}

// ---- conv3x3 (8->16, pad1) + maxpool2 + sigmoid -> X2[16,16,128,128] ----
__global__ __launch_bounds__(256) void k_conv2p(
    const float* __restrict__ X1, const float* __restrict__ w, const float* __restrict__ bias,
    float* __restrict__ X2)
{
  const int n  = blockIdx.y;
  const int wo = threadIdx.x & 127;
  const int ho = blockIdx.x*2 + (threadIdx.x>>7);
  float acc[16][4];
#pragma unroll
  for (int co=0;co<16;++co){
    float bb = bias[co];
    acc[co][0]=bb; acc[co][1]=bb; acc[co][2]=bb; acc[co][3]=bb;
  }
#pragma unroll 1
  for (int ci=0; ci<8; ++ci){
    const float* p = X1 + ((size_t)(n*8+ci))*65536;
    float patch[4][4];
#pragma unroll
    for (int dy=0;dy<4;++dy){
      int r = 2*ho-1+dy;
      bool rok = (r>=0 && r<256);
#pragma unroll
      for (int dx=0;dx<4;++dx){
        int cc = 2*wo-1+dx;
        patch[dy][dx] = (rok && cc>=0 && cc<256) ? p[r*256+cc] : 0.f;
      }
    }
#pragma unroll
    for (int co=0;co<16;++co){
      const float* wp = w + (co*8+ci)*9;
#pragma unroll
      for (int py=0;py<2;++py)
#pragma unroll
      for (int px=0;px<2;++px){
        float a = acc[co][py*2+px];
#pragma unroll
        for (int kh=0;kh<3;++kh)
#pragma unroll
        for (int kw=0;kw<3;++kw)
          a += wp[kh*3+kw]*patch[py+kh][px+kw];
        acc[co][py*2+px] = a;
      }
    }
  }
#pragma unroll
  for (int co=0;co<16;++co){
    float m = fmaxf(fmaxf(acc[co][0],acc[co][1]), fmaxf(acc[co][2],acc[co][3]));
    X2[((size_t)(n*16+co)*128 + ho)*128 + wo] = sgm(m);
  }
}

// ---- stats of relu(upsample4(X2)) over [16,16,512,512]; per-(n,c) partials ----
__global__ __launch_bounds__(256) void k_stats_up4(
    const float* __restrict__ X2, double* __restrict__ SB1)
{
  const int n = blockIdx.z, c = blockIdx.y;
  const float* p = X2 + ((size_t)(n*16+c))*16384;
  const int id = blockIdx.x*256 + threadIdx.x;     // 0..65535
  const int ho = id>>7, m = id&127;                 // out row, col-group (4 cols)
  const int q = ho>>2, r = ho&3;
  int rA, rB; float wA;
  if (r==0){ rA=q-1; rB=q;   wA=0.375f; }
  else if (r==1){ rA=q-1; rB=q;   wA=0.125f; }
  else if (r==2){ rA=q;   rB=q+1; wA=0.875f; }
  else          { rA=q;   rB=q+1; wA=0.625f; }
  const float wB = 1.f-wA;
  rA = max(rA,0); rB = min(rB,127);
  const int c0 = max(m-1,0), c1 = m, c2 = min(m+1,127);
  const float* pa = p + rA*128; const float* pb = p + rB*128;
  float t0 = wA*pa[c0]+wB*pb[c0];
  float t1 = wA*pa[c1]+wB*pb[c1];
  float t2 = wA*pa[c2]+wB*pb[c2];
  float o0 = fmaxf(0.375f*t0+0.625f*t1, 0.f);
  float o1 = fmaxf(0.125f*t0+0.875f*t1, 0.f);
  float o2 = fmaxf(0.875f*t1+0.125f*t2, 0.f);
  float o3 = fmaxf(0.625f*t1+0.375f*t2, 0.f);
  float sum = o0+o1+o2+o3;
  float sq  = o0*o0+o1*o1+o2*o2+o3*o3;
  __shared__ float red[4][2];
  const int lane = threadIdx.x & 63, wid = threadIdx.x >> 6;
  for (int off=32; off>0; off>>=1){ sum += __shfl_down(sum,off); sq += __shfl_down(sq,off); }
  if (lane==0){ red[wid][0]=sum; red[wid][1]=sq; }
  __syncthreads();
  if (threadIdx.x < 2){
    int k = threadIdx.x;
    float t = red[0][k]+red[1][k]+red[2][k]+red[3][k];
    atomicAdd(&SB1[(n*16+c)*2+k], (double)t);
  }
}

// ---- stats of relu(upsample2(X1)) over [16,8,512,512]; per-(n,c) partials ----
__global__ __launch_bounds__(256) void k_stats_up2(
    const float* __restrict__ X1, double* __restrict__ SB2)
{
  const int n = blockIdx.z, c = blockIdx.y;
  const float* p = X1 + ((size_t)(n*8+c))*65536;
  const int id = blockIdx.x*256 + threadIdx.x;     // 0..65535
  const int ho = id>>7, m = id&127;
  const int i = ho>>1, r = ho&1;
  int rA, rB; float wA;
  if (r==0){ rA=i-1; rB=i;   wA=0.25f; }
  else     { rA=i;   rB=i+1; wA=0.75f; }
  const float wB = 1.f-wA;
  rA = max(rA,0); rB = min(rB,255);
  const int c0 = max(2*m-1,0), c1 = 2*m, c2 = 2*m+1, c3 = min(2*m+2,255);
  const float* pa = p + rA*256; const float* pb = p + rB*256;
  float t0 = wA*pa[c0]+wB*pb[c0];
  float t1 = wA*pa[c1]+wB*pb[c1];
  float t2 = wA*pa[c2]+wB*pb[c2];
  float t3 = wA*pa[c3]+wB*pb[c3];
  float o0 = fmaxf(0.25f*t0+0.75f*t1, 0.f);
  float o1 = fmaxf(0.75f*t1+0.25f*t2, 0.f);
  float o2 = fmaxf(0.25f*t1+0.75f*t2, 0.f);
  float o3 = fmaxf(0.75f*t2+0.25f*t3, 0.f);
  float sum = o0+o1+o2+o3;
  float sq  = o0*o0+o1*o1+o2*o2+o3*o3;
  __shared__ float red[4][2];
  const int lane = threadIdx.x & 63, wid = threadIdx.x >> 6;
  for (int off=32; off>0; off>>=1){ sum += __shfl_down(sum,off); sq += __shfl_down(sq,off); }
  if (lane==0){ red[wid][0]=sum; red[wid][1]=sq; }
  __syncthreads();
  if (threadIdx.x < 2){
    int k = threadIdx.x;
    float t = red[0][k]+red[1][k]+red[2][k]+red[3][k];
    atomicAdd(&SB2[(n*8+c)*2+k], (double)t);
  }
}

// ---- final: on-the-fly up2/up4 + relu + BN + concat + 1x1 conv (24->5) ----
__global__ __launch_bounds__(256) void k_final(
    const float* __restrict__ X1, const float* __restrict__ X2,
    const float* __restrict__ ABB1, const float* __restrict__ ABB2,
    const float* __restrict__ w1k, const float* __restrict__ b1k,
    float* __restrict__ out)
{
  const int n = blockIdx.y;
  const int id = blockIdx.x*256 + threadIdx.x;     // 0..65535
  const int h = id>>7, m = id&127;                  // out row, 4-col group
  float acc[5][4];
#pragma unroll
  for (int cls=0;cls<5;++cls){
    float bb = b1k[cls];
    acc[cls][0]=bb; acc[cls][1]=bb; acc[cls][2]=bb; acc[cls][3]=bb;
  }
  // x1 path (channels 0..7 of merge): upsample2
  {
    const int i = h>>1, r = h&1;
    int rA,rB; float wA;
    if (r==0){ rA=i-1; rB=i;   wA=0.25f; } else { rA=i; rB=i+1; wA=0.75f; }
    const float wB = 1.f-wA;
    rA = max(rA,0); rB = min(rB,255);
    const int c0 = max(2*m-1,0), c1 = 2*m, c2 = 2*m+1, c3 = min(2*m+2,255);
#pragma unroll
    for (int c=0;c<8;++c){
      const float* p  = X1 + ((size_t)(n*8+c))*65536;
      const float* pa = p + rA*256; const float* pb = p + rB*256;
      float t0 = wA*pa[c0]+wB*pb[c0];
      float t1 = wA*pa[c1]+wB*pb[c1];
      float t2 = wA*pa[c2]+wB*pb[c2];
      float t3 = wA*pa[c3]+wB*pb[c3];
      float o0 = 0.25f*t0+0.75f*t1, o1 = 0.75f*t1+0.25f*t2;
      float o2 = 0.25f*t1+0.75f*t2, o3 = 0.75f*t2+0.25f*t3;
      const float a = ABB2[c], bb = ABB2[8+c];
      o0 = a*fmaxf(o0,0.f)+bb; o1 = a*fmaxf(o1,0.f)+bb;
      o2 = a*fmaxf(o2,0.f)+bb; o3 = a*fmaxf(o3,0.f)+bb;
#pragma unroll
      for (int cls=0;cls<5;++cls){
        float wv = w1k[cls*24+c];
        acc[cls][0]+=wv*o0; acc[cls][1]+=wv*o1; acc[cls][2]+=wv*o2; acc[cls][3]+=wv*o3;
      }
    }
  }
  // x2 path (channels 8..23 of merge): upsample4
  {
    const int q = h>>2, r = h&3;
    int rA,rB; float wA;
    if (r==0){ rA=q-1; rB=q;   wA=0.375f; }
    else if (r==1){ rA=q-1; rB=q;   wA=0.125f; }
    else if (r==2){ rA=q;   rB=q+1; wA=0.875f; }
    else          { rA=q;   rB=q+1; wA=0.625f; }
    const float wB = 1.f-wA;
    rA = max(rA,0); rB = min(rB,127);
    const int c0 = max(m-1,0), c1 = m, c2 = min(m+1,127);
#pragma unroll
    for (int c=0;c<16;++c){
      const float* p  = X2 + ((size_t)(n*16+c))*16384;
      const float* pa = p + rA*128; const float* pb = p + rB*128;
      float t0 = wA*pa[c0]+wB*pb[c0];
      float t1 = wA*pa[c1]+wB*pb[c1];
      float t2 = wA*pa[c2]+wB*pb[c2];
      float o0 = 0.375f*t0+0.625f*t1;
      float o1 = 0.125f*t0+0.875f*t1;
      float o2 = 0.875f*t1+0.125f*t2;
      float o3 = 0.625f*t1+0.375f*t2;
      const float a = ABB1[c], bb = ABB1[16+c];
      o0 = a*fmaxf(o0,0.f)+bb; o1 = a*fmaxf(o1,0.f)+bb;
      o2 = a*fmaxf(o2,0.f)+bb; o3 = a*fmaxf(o3,0.f)+bb;
#pragma unroll
      for (int cls=0;cls<5;++cls){
        float wv = w1k[cls*24+8+c];
        acc[cls][0]+=wv*o0; acc[cls][1]+=wv*o1; acc[cls][2]+=wv*o2; acc[cls][3]+=wv*o3;
      }
    }
  }
#pragma unroll
  for (int cls=0;cls<5;++cls){
    float4 v; v.x=acc[cls][0]; v.y=acc[cls][1]; v.z=acc[cls][2]; v.w=acc[cls][3];
    *(float4*)(out + ((size_t)(n*5+cls))*HW_ + (size_t)h*W_ + 4*m) = v;
  }
}

extern "C" void kernel_launch(void* const* d_in, const int* in_sizes, int n_in,
                              void* d_out, int out_size, void* d_ws, size_t ws_size,
                              hipStream_t stream) {
  const float* x       = (const float*)d_in[0];
  const float* w_ext1  = (const float*)d_in[1];
  const float* b_ext1  = (const float*)d_in[2];
  const float* g_ebn1  = (const float*)d_in[3];
  const float* be_ebn1 = (const float*)d_in[4];
  const float* w_ext2  = (const float*)d_in[5];
  const float* b_ext2  = (const float*)d_in[6];
  const float* g_ebn2  = (const float*)d_in[7];
  const float* be_ebn2 = (const float*)d_in[8];
  const float* w_c1    = (const float*)d_in[9];
  const float* b_c1    = (const float*)d_in[10];
  const float* w_c2    = (const float*)d_in[11];
  const float* b_c2    = (const float*)d_in[12];
  const float* g_bn1   = (const float*)d_in[13];
  const float* be_bn1  = (const float*)d_in[14];
  const float* g_bn2   = (const float*)d_in[15];
  const float* be_bn2  = (const float*)d_in[16];
  const float* w_1k    = (const float*)d_in[17];
  const float* b_1k    = (const float*)d_in[18];
  float* outp = (float*)d_out;

  char* ws = (char*)d_ws;
  float* B  = (float*)ws;                                   // 16*16*512*512 f = 268435456 B
  float* X1 = (float*)(ws + 268435456);                     // 16*8*256*256 f = 33554432 B
  float* X2 = (float*)(ws + 268435456 + 33554432);          // 16*16*128*128 f = 16777216 B
  char*  sb = ws + 268435456 + 33554432 + 16777216;         // 8-aligned
  double* S1  = (double*)sb;        // 512
  double* S2  = S1  + 512;          // 512
  double* SV  = S2  + 512;          // 512
  double* SB1 = SV  + 512;          // 512
  double* SB2 = SB1 + 512;          // 256
  float*  AB1  = (float*)(SB2 + 256);  // 32
  float*  AB2  = AB1 + 32;             // 32
  float*  ABB1 = AB2 + 32;             // 32
  float*  ABB2 = ABB1 + 32;            // 16
  int*    IDX  = (int*)(ABB2 + 16);    // 48

  const double invM_bn = 1.0/4194304.0;   // N*H*W per channel

  k_zero<<<1,256,0,stream>>>(S1, 2304);
  k_stats1<<<dim3(64,16),256,0,stream>>>(x, w_ext1, b_ext1, S1);
  k_fin<<<1,64,0,stream>>>(S1, g_ebn1, be_ebn1, AB1, 16, invM_bn);
  k_band2<<<dim3(64,16),256,0,stream>>>(x, w_ext1, b_ext1, AB1, w_ext2, b_ext2, B, S2);
  k_fin<<<1,64,0,stream>>>(S2, g_ebn2, be_ebn2, AB2, 16, invM_bn);
  k_bnsig<<<dim3(64,16,16),256,0,stream>>>(B, AB2, SV);
  k_topk<<<1,256,0,stream>>>(SV, IDX);
  k_conv1p<<<dim3(256,16),256,0,stream>>>(B, IDX, w_c1, b_c1, X1);
  k_conv2p<<<dim3(64,16),256,0,stream>>>(X1, w_c2, b_c2, X2);
  k_stats_up4<<<dim3(256,16,16),256,0,stream>>>(X2, SB1);
  k_stats_up2<<<dim3(256,8,16),256,0,stream>>>(X1, SB2);
  k_fin<<<1,64,0,stream>>>(SB1, g_bn1, be_bn1, ABB1, 16, invM_bn);
  k_fin<<<1,64,0,stream>>>(SB2, g_bn2, be_bn2, ABB2, 8, invM_bn);
  k_final<<<dim3(256,16),256,0,stream>>>(X1, X2, ABB1, ABB2, w_1k, b_1k, outp);
}

// Round 3
// 818.293 us; speedup vs baseline: 1.1076x; 1.1076x over previous
//
#include <hip/hip_runtime.h>
#include <math.h>

#define N_    16
#define CIN_  10
#define CB_   16
#define H_    512
#define W_    512
#define HW_   (512*512)
#define EPSF  1e-5f

// fast sigmoid: v_mul + v_exp + v_add + v_rcp (vs ~22-instr libm expf + IEEE div)
__device__ __forceinline__ float sgm(float z){
  float e = __builtin_amdgcn_exp2f(z * -1.44269504088896f);
  return __builtin_amdgcn_rcpf(1.0f + e);
}

// ---------------- zero stats ----------------
__global__ void k_zero(double* __restrict__ p, int n){
  int i = blockIdx.x*256 + threadIdx.x;
  if (i < n) p[i] = 0.0;
}

// ---------------- finalize BN affine from per-(n,c) sum/sumsq ----------------
__global__ void k_fin(const double* __restrict__ S, const float* __restrict__ g,
                      const float* __restrict__ be, float* __restrict__ AB,
                      int C, double invM){
  int c = threadIdx.x;
  if (c < C){
    double s=0.0,q=0.0;
    for (int n=0;n<N_;++n){ s+=S[(n*C+c)*2]; q+=S[(n*C+c)*2+1]; }
    double mean = s*invM;
    double var  = q*invM - mean*mean;
    float a = g[c]*rsqrtf((float)var + EPSF);
    AB[c]   = a;
    AB[C+c] = be[c] - (float)mean*a;
  }
}

// ---- pass 1: channel sums + pair products of x (BN1 stats in closed form) ----
__global__ __launch_bounds__(256) void k_cov(
    const float* __restrict__ x, double* __restrict__ SP)
{
  const int n = blockIdx.y;
  const int base = blockIdx.x*4096;
  const float* xp = x + (size_t)n*CIN_*HW_;
  float s[CIN_], p[55];
#pragma unroll
  for (int i=0;i<CIN_;++i) s[i]=0.f;
#pragma unroll
  for (int i=0;i<55;++i) p[i]=0.f;
#pragma unroll 1
  for (int it=0; it<4; ++it){
    const int off = base + it*1024 + threadIdx.x*4;
    float4 xv[CIN_];
#pragma unroll
    for (int ci=0; ci<CIN_; ++ci)
      xv[ci] = *(const float4*)(xp + (size_t)ci*HW_ + off);
#pragma unroll
    for (int ci=0; ci<CIN_; ++ci)
      s[ci] += xv[ci].x + xv[ci].y + xv[ci].z + xv[ci].w;
    int k=0;
#pragma unroll
    for (int i=0;i<CIN_;++i)
#pragma unroll
      for (int j=i;j<CIN_;++j,++k)
        p[k] += xv[i].x*xv[j].x + xv[i].y*xv[j].y + xv[i].z*xv[j].z + xv[i].w*xv[j].w;
  }
  __shared__ float red[4][65];
  const int lane = threadIdx.x & 63, wid = threadIdx.x >> 6;
#pragma unroll
  for (int k=0;k<65;++k){
    float v = (k<CIN_) ? s[k] : p[k-CIN_];
    for (int o=32;o>0;o>>=1) v += __shfl_down(v,o);
    if (lane==0) red[wid][k]=v;
  }
  __syncthreads();
  if (threadIdx.x < 65){
    float v = red[0][threadIdx.x]+red[1][threadIdx.x]+red[2][threadIdx.x]+red[3][threadIdx.x];
    atomicAdd(&SP[n*65+threadIdx.x], (double)v);
  }
}

// ---- finalize BN1 from covariance: mean/var of b + w.x per out-channel ----
// NOTE: must run with >= 65 threads (65 reduction slots). Round-2 bug: 64 threads
// left Cv[54] (= E[x9^2] term) uninitialized -> corrupted AB1. Launch with 128.
__global__ void k_fin1(const double* __restrict__ SP, const float* __restrict__ w1,
                       const float* __restrict__ b1, const float* __restrict__ g,
                       const float* __restrict__ be, float* __restrict__ AB){
  __shared__ double Sm[CIN_], Cv[55];
  int t = threadIdx.x;
  if (t < 65){
    double s = 0.0;
    for (int n=0;n<N_;++n) s += SP[n*65+t];
    if (t < CIN_) Sm[t] = s; else Cv[t-CIN_] = s;
  }
  __syncthreads();
  if (t < CB_){
    const double M = 16.0*(double)HW_;
    double b = (double)b1[t];
    double wd[CIN_];
    double lin = 0.0;
    for (int i=0;i<CIN_;++i){ wd[i] = (double)w1[t*CIN_+i]; lin += wd[i]*Sm[i]/M; }
    double mean = b + lin;
    double ey2 = b*b + 2.0*b*lin;
    int k=0;
    for (int i=0;i<CIN_;++i)
      for (int j=i;j<CIN_;++j,++k)
        ey2 += (i==j ? 1.0 : 2.0) * wd[i]*wd[j]*(Cv[k]/M);
    double var = ey2 - mean*mean;
    float a = g[t]*rsqrtf((float)var + EPSF);
    AB[t] = a;
    AB[CB_+t] = be[t] - (float)mean*a;
  }
}

// ---- pass 2: conv1 -> BN1 -> sigmoid -> conv2 (1x1); write pre-BN2 B; stats2 ----
__global__ __launch_bounds__(256) void k_band2(
    const float* __restrict__ x,
    const float* __restrict__ w1, const float* __restrict__ b1, const float* __restrict__ AB1,
    const float* __restrict__ w2, const float* __restrict__ b2,
    float* __restrict__ B, double* __restrict__ S2)
{
  const int n = blockIdx.y;
  const int base = blockIdx.x*4096;
  const float* xp = x + (size_t)n*CIN_*HW_;
  float* bp = B + (size_t)n*CB_*HW_;
  float sum[CB_], sq[CB_];
#pragma unroll
  for (int c=0;c<CB_;++c){ sum[c]=0.f; sq[c]=0.f; }
#pragma unroll 1
  for (int it=0; it<4; ++it){
    const int p = base + it*1024 + threadIdx.x*4;
    float4 xv[CIN_];
#pragma unroll
    for (int ci=0; ci<CIN_; ++ci)
      xv[ci] = *(const float4*)(xp + (size_t)ci*HW_ + p);
    float4 s[CB_];
#pragma unroll
    for (int co=0; co<CB_; ++co){
      float bb = b1[co];
      float ox=bb, oy=bb, oz=bb, ow=bb;
#pragma unroll
      for (int ci=0; ci<CIN_; ++ci){
        float w = w1[co*CIN_+ci];
        ox += w*xv[ci].x; oy += w*xv[ci].y; oz += w*xv[ci].z; ow += w*xv[ci].w;
      }
      const float a = AB1[co], sh = AB1[CB_+co];
      s[co].x = sgm(a*ox+sh); s[co].y = sgm(a*oy+sh);
      s[co].z = sgm(a*oz+sh); s[co].w = sgm(a*ow+sh);
    }
#pragma unroll
    for (int co=0; co<CB_; ++co){
      float bb = b2[co];
      float ox=bb, oy=bb, oz=bb, ow=bb;
#pragma unroll
      for (int ci=0; ci<CB_; ++ci){
        float w = w2[co*CB_+ci];
        ox += w*s[ci].x; oy += w*s[ci].y; oz += w*s[ci].z; ow += w*s[ci].w;
      }
      float4 o; o.x=ox; o.y=oy; o.z=oz; o.w=ow;
      *(float4*)(bp + (size_t)co*HW_ + p) = o;
      sum[co] += ox+oy+oz+ow;
      sq[co]  += ox*ox+oy*oy+oz*oz+ow*ow;
    }
  }
  __shared__ float red[4][CB_][2];
  const int lane = threadIdx.x & 63, wid = threadIdx.x >> 6;
#pragma unroll
  for (int c=0;c<CB_;++c){
    float s=sum[c], q=sq[c];
    for (int off=32; off>0; off>>=1){ s += __shfl_down(s,off); q += __shfl_down(q,off); }
    if (lane==0){ red[wid][c][0]=s; red[wid][c][1]=q; }
  }
  __syncthreads();
  if (threadIdx.x < CB_*2){
    int c = threadIdx.x>>1, k = threadIdx.x&1;
    float t = red[0][c][k]+red[1][c][k]+red[2][c][k]+red[3][c][k];
    atomicAdd(&S2[(n*CB_+c)*2+k], (double)t);
  }
}

// ---- pass 3 (stats only): per-(n,c) sum/sumsq of sigmoid(BN2(B)); no write-back ----
__global__ __launch_bounds__(256) void k_varstats(
    const float* __restrict__ B, const float* __restrict__ AB2, double* __restrict__ SV)
{
  const int n = blockIdx.z, c = blockIdx.y;
  const float a = AB2[c], b = AB2[CB_+c];
  const float* p = B + ((size_t)(n*CB_+c))*HW_ + blockIdx.x*4096;
  float sum=0.f, sq=0.f;
#pragma unroll 1
  for (int it=0; it<4; ++it){
    float4 v = *(const float4*)(p + it*1024 + threadIdx.x*4);
    v.x = sgm(a*v.x+b); v.y = sgm(a*v.y+b); v.z = sgm(a*v.z+b); v.w = sgm(a*v.w+b);
    sum += v.x+v.y+v.z+v.w;
    sq  += v.x*v.x+v.y*v.y+v.z*v.z+v.w*v.w;
  }
  __shared__ float red[4][2];
  const int lane = threadIdx.x & 63, wid = threadIdx.x >> 6;
  for (int off=32; off>0; off>>=1){ sum += __shfl_down(sum,off); sq += __shfl_down(sq,off); }
  if (lane==0){ red[wid][0]=sum; red[wid][1]=sq; }
  __syncthreads();
  if (threadIdx.x < 2){
    int k = threadIdx.x;
    float t = red[0][k]+red[1][k]+red[2][k]+red[3][k];
    atomicAdd(&SV[(n*CB_+c)*2+k], (double)t);
  }
}

// ---- top-3 per-sample channels by unbiased variance (stable ties: lowest idx) ----
__global__ void k_topk(const double* __restrict__ SV, int* __restrict__ IDX){
  __shared__ double var[N_][CB_];
  int t = threadIdx.x;
  if (t < N_*CB_){
    int n=t>>4, c=t&15;
    double s=SV[t*2], q=SV[t*2+1];
    const double M = (double)HW_;
    var[n][c] = (q - s*s/M)/(M-1.0);
  }
  __syncthreads();
  if (t < N_){
    double v[CB_];
#pragma unroll
    for (int c=0;c<CB_;++c) v[c]=var[t][c];
    for (int k=0;k<3;++k){
      int bi=0; double bv=v[0];
#pragma unroll
      for (int c=1;c<CB_;++c) if (v[c]>bv){ bv=v[c]; bi=c; }
      IDX[t*3+k]=bi; v[bi]=-1e300;
    }
  }
}

// ---- conv3x3 (3->8, pad1) + maxpool2 + sigmoid; BN2+sigmoid applied inline on load ----
__global__ __launch_bounds__(256) void k_conv1p(
    const float* __restrict__ B, const int* __restrict__ IDX, const float* __restrict__ AB2,
    const float* __restrict__ w, const float* __restrict__ bias,
    float* __restrict__ X1)
{
  const int n = blockIdx.y, ho = blockIdx.x, wo = threadIdx.x;
  __shared__ int chs[3];
  __shared__ float ca[3], cb[3];
  if (threadIdx.x < 3){
    int c = IDX[n*3+threadIdx.x];
    chs[threadIdx.x] = c;
    ca[threadIdx.x] = AB2[c];
    cb[threadIdx.x] = AB2[CB_+c];
  }
  __syncthreads();
  float in[3][4][4];
#pragma unroll
  for (int k=0;k<3;++k){
    const float* pc = B + ((size_t)(n*CB_+chs[k]))*HW_;
    const float a = ca[k], bb = cb[k];
#pragma unroll
    for (int dy=0;dy<4;++dy){
      int r = 2*ho-1+dy;
      bool rok = (r>=0 && r<H_);
#pragma unroll
      for (int dx=0;dx<4;++dx){
        int cc = 2*wo-1+dx;
        in[k][dy][dx] = (rok && cc>=0 && cc<W_) ? sgm(a*pc[(size_t)r*W_+cc]+bb) : 0.f;
      }
    }
  }
#pragma unroll
  for (int co=0;co<8;++co){
    float m = -1e30f;
#pragma unroll
    for (int py=0;py<2;++py)
#pragma unroll
    for (int px=0;px<2;++px){
      float acc = bias[co];
#pragma unroll
      for (int k=0;k<3;++k)
#pragma unroll
      for (int kh=0;kh<3;++kh)
#pragma unroll
      for (int kw=0;kw<3;++kw)
        acc += w[((co*3+k)*3+kh)*3+kw] * in[k][py+kh][px+kw];
      m = fmaxf(m, acc);
    }
    X1[((size_t)(n*8+co)*256 + ho)*256 + wo] = sgm(m);
  }
}

// ---- conv3x3 (8->16, pad1) + maxpool2 + sigmoid -> X2[16,16,128,128] ----
__global__ __launch_bounds__(256) void k_conv2p(
    const float* __restrict__ X1, const float* __restrict__ w, const float* __restrict__ bias,
    float* __restrict__ X2)
{
  const int n  = blockIdx.y;
  const int wo = threadIdx.x & 127;
  const int ho = blockIdx.x*2 + (threadIdx.x>>7);
  float acc[16][4];
#pragma unroll
  for (int co=0;co<16;++co){
    float bb = bias[co];
    acc[co][0]=bb; acc[co][1]=bb; acc[co][2]=bb; acc[co][3]=bb;
  }
#pragma unroll 1
  for (int ci=0; ci<8; ++ci){
    const float* p = X1 + ((size_t)(n*8+ci))*65536;
    float patch[4][4];
#pragma unroll
    for (int dy=0;dy<4;++dy){
      int r = 2*ho-1+dy;
      bool rok = (r>=0 && r<256);
#pragma unroll
      for (int dx=0;dx<4;++dx){
        int cc = 2*wo-1+dx;
        patch[dy][dx] = (rok && cc>=0 && cc<256) ? p[r*256+cc] : 0.f;
      }
    }
#pragma unroll
    for (int co=0;co<16;++co){
      const float* wp = w + (co*8+ci)*9;
#pragma unroll
      for (int py=0;py<2;++py)
#pragma unroll
      for (int px=0;px<2;++px){
        float a = acc[co][py*2+px];
#pragma unroll
        for (int kh=0;kh<3;++kh)
#pragma unroll
        for (int kw=0;kw<3;++kw)
          a += wp[kh*3+kw]*patch[py+kh][px+kw];
        acc[co][py*2+px] = a;
      }
    }
  }
#pragma unroll
  for (int co=0;co<16;++co){
    float m = fmaxf(fmaxf(acc[co][0],acc[co][1]), fmaxf(acc[co][2],acc[co][3]));
    X2[((size_t)(n*16+co)*128 + ho)*128 + wo] = sgm(m);
  }
}

// ---- stats of relu(upsample4(X2)) ----
__global__ __launch_bounds__(256) void k_stats_up4(
    const float* __restrict__ X2, double* __restrict__ SB1)
{
  const int n = blockIdx.z, c = blockIdx.y;
  const float* p = X2 + ((size_t)(n*16+c))*16384;
  const int id = blockIdx.x*256 + threadIdx.x;
  const int ho = id>>7, m = id&127;
  const int q = ho>>2, r = ho&3;
  int rA, rB; float wA;
  if (r==0){ rA=q-1; rB=q;   wA=0.375f; }
  else if (r==1){ rA=q-1; rB=q;   wA=0.125f; }
  else if (r==2){ rA=q;   rB=q+1; wA=0.875f; }
  else          { rA=q;   rB=q+1; wA=0.625f; }
  const float wB = 1.f-wA;
  rA = max(rA,0); rB = min(rB,127);
  const int c0 = max(m-1,0), c1 = m, c2 = min(m+1,127);
  const float* pa = p + rA*128; const float* pb = p + rB*128;
  float t0 = wA*pa[c0]+wB*pb[c0];
  float t1 = wA*pa[c1]+wB*pb[c1];
  float t2 = wA*pa[c2]+wB*pb[c2];
  float o0 = fmaxf(0.375f*t0+0.625f*t1, 0.f);
  float o1 = fmaxf(0.125f*t0+0.875f*t1, 0.f);
  float o2 = fmaxf(0.875f*t1+0.125f*t2, 0.f);
  float o3 = fmaxf(0.625f*t1+0.375f*t2, 0.f);
  float sum = o0+o1+o2+o3;
  float sq  = o0*o0+o1*o1+o2*o2+o3*o3;
  __shared__ float red[4][2];
  const int lane = threadIdx.x & 63, wid = threadIdx.x >> 6;
  for (int off=32; off>0; off>>=1){ sum += __shfl_down(sum,off); sq += __shfl_down(sq,off); }
  if (lane==0){ red[wid][0]=sum; red[wid][1]=sq; }
  __syncthreads();
  if (threadIdx.x < 2){
    int k = threadIdx.x;
    float t = red[0][k]+red[1][k]+red[2][k]+red[3][k];
    atomicAdd(&SB1[(n*16+c)*2+k], (double)t);
  }
}

// ---- stats of relu(upsample2(X1)) ----
__global__ __launch_bounds__(256) void k_stats_up2(
    const float* __restrict__ X1, double* __restrict__ SB2)
{
  const int n = blockIdx.z, c = blockIdx.y;
  const float* p = X1 + ((size_t)(n*8+c))*65536;
  const int id = blockIdx.x*256 + threadIdx.x;
  const int ho = id>>7, m = id&127;
  const int i = ho>>1, r = ho&1;
  int rA, rB; float wA;
  if (r==0){ rA=i-1; rB=i;   wA=0.25f; }
  else     { rA=i;   rB=i+1; wA=0.75f; }
  const float wB = 1.f-wA;
  rA = max(rA,0); rB = min(rB,255);
  const int c0 = max(2*m-1,0), c1 = 2*m, c2 = 2*m+1, c3 = min(2*m+2,255);
  const float* pa = p + rA*256; const float* pb = p + rB*256;
  float t0 = wA*pa[c0]+wB*pb[c0];
  float t1 = wA*pa[c1]+wB*pb[c1];
  float t2 = wA*pa[c2]+wB*pb[c2];
  float t3 = wA*pa[c3]+wB*pb[c3];
  float o0 = fmaxf(0.25f*t0+0.75f*t1, 0.f);
  float o1 = fmaxf(0.75f*t1+0.25f*t2, 0.f);
  float o2 = fmaxf(0.25f*t1+0.75f*t2, 0.f);
  float o3 = fmaxf(0.75f*t2+0.25f*t3, 0.f);
  float sum = o0+o1+o2+o3;
  float sq  = o0*o0+o1*o1+o2*o2+o3*o3;
  __shared__ float red[4][2];
  const int lane = threadIdx.x & 63, wid = threadIdx.x >> 6;
  for (int off=32; off>0; off>>=1){ sum += __shfl_down(sum,off); sq += __shfl_down(sq,off); }
  if (lane==0){ red[wid][0]=sum; red[wid][1]=sq; }
  __syncthreads();
  if (threadIdx.x < 2){
    int k = threadIdx.x;
    float t = red[0][k]+red[1][k]+red[2][k]+red[3][k];
    atomicAdd(&SB2[(n*8+c)*2+k], (double)t);
  }
}

// ---- final: on-the-fly up2/up4 + relu + BN + concat + 1x1 conv (24->5) ----
__global__ __launch_bounds__(256) void k_final(
    const float* __restrict__ X1, const float* __restrict__ X2,
    const float* __restrict__ ABB1, const float* __restrict__ ABB2,
    const float* __restrict__ w1k, const float* __restrict__ b1k,
    float* __restrict__ out)
{
  const int n = blockIdx.y;
  const int id = blockIdx.x*256 + threadIdx.x;
  const int h = id>>7, m = id&127;
  float acc[5][4];
#pragma unroll
  for (int cls=0;cls<5;++cls){
    float bb = b1k[cls];
    acc[cls][0]=bb; acc[cls][1]=bb; acc[cls][2]=bb; acc[cls][3]=bb;
  }
  {
    const int i = h>>1, r = h&1;
    int rA,rB; float wA;
    if (r==0){ rA=i-1; rB=i;   wA=0.25f; } else { rA=i; rB=i+1; wA=0.75f; }
    const float wB = 1.f-wA;
    rA = max(rA,0); rB = min(rB,255);
    const int c0 = max(2*m-1,0), c1 = 2*m, c2 = 2*m+1, c3 = min(2*m+2,255);
#pragma unroll
    for (int c=0;c<8;++c){
      const float* p  = X1 + ((size_t)(n*8+c))*65536;
      const float* pa = p + rA*256; const float* pb = p + rB*256;
      float t0 = wA*pa[c0]+wB*pb[c0];
      float t1 = wA*pa[c1]+wB*pb[c1];
      float t2 = wA*pa[c2]+wB*pb[c2];
      float t3 = wA*pa[c3]+wB*pb[c3];
      float o0 = 0.25f*t0+0.75f*t1, o1 = 0.75f*t1+0.25f*t2;
      float o2 = 0.25f*t1+0.75f*t2, o3 = 0.75f*t2+0.25f*t3;
      const float a = ABB2[c], bb = ABB2[8+c];
      o0 = a*fmaxf(o0,0.f)+bb; o1 = a*fmaxf(o1,0.f)+bb;
      o2 = a*fmaxf(o2,0.f)+bb; o3 = a*fmaxf(o3,0.f)+bb;
#pragma unroll
      for (int cls=0;cls<5;++cls){
        float wv = w1k[cls*24+c];
        acc[cls][0]+=wv*o0; acc[cls][1]+=wv*o1; acc[cls][2]+=wv*o2; acc[cls][3]+=wv*o3;
      }
    }
  }
  {
    const int q = h>>2, r = h&3;
    int rA,rB; float wA;
    if (r==0){ rA=q-1; rB=q;   wA=0.375f; }
    else if (r==1){ rA=q-1; rB=q;   wA=0.125f; }
    else if (r==2){ rA=q;   rB=q+1; wA=0.875f; }
    else          { rA=q;   rB=q+1; wA=0.625f; }
    const float wB = 1.f-wA;
    rA = max(rA,0); rB = min(rB,127);
    const int c0 = max(m-1,0), c1 = m, c2 = min(m+1,127);
#pragma unroll
    for (int c=0;c<16;++c){
      const float* p  = X2 + ((size_t)(n*16+c))*16384;
      const float* pa = p + rA*128; const float* pb = p + rB*128;
      float t0 = wA*pa[c0]+wB*pb[c0];
      float t1 = wA*pa[c1]+wB*pb[c1];
      float t2 = wA*pa[c2]+wB*pb[c2];
      float o0 = 0.375f*t0+0.625f*t1;
      float o1 = 0.125f*t0+0.875f*t1;
      float o2 = 0.875f*t1+0.125f*t2;
      float o3 = 0.625f*t1+0.375f*t2;
      const float a = ABB1[c], bb = ABB1[16+c];
      o0 = a*fmaxf(o0,0.f)+bb; o1 = a*fmaxf(o1,0.f)+bb;
      o2 = a*fmaxf(o2,0.f)+bb; o3 = a*fmaxf(o3,0.f)+bb;
#pragma unroll
      for (int cls=0;cls<5;++cls){
        float wv = w1k[cls*24+8+c];
        acc[cls][0]+=wv*o0; acc[cls][1]+=wv*o1; acc[cls][2]+=wv*o2; acc[cls][3]+=wv*o3;
      }
    }
  }
#pragma unroll
  for (int cls=0;cls<5;++cls){
    float4 v; v.x=acc[cls][0]; v.y=acc[cls][1]; v.z=acc[cls][2]; v.w=acc[cls][3];
    *(float4*)(out + ((size_t)(n*5+cls))*HW_ + (size_t)h*W_ + 4*m) = v;
  }
}

extern "C" void kernel_launch(void* const* d_in, const int* in_sizes, int n_in,
                              void* d_out, int out_size, void* d_ws, size_t ws_size,
                              hipStream_t stream) {
  const float* x       = (const float*)d_in[0];
  const float* w_ext1  = (const float*)d_in[1];
  const float* b_ext1  = (const float*)d_in[2];
  const float* g_ebn1  = (const float*)d_in[3];
  const float* be_ebn1 = (const float*)d_in[4];
  const float* w_ext2  = (const float*)d_in[5];
  const float* b_ext2  = (const float*)d_in[6];
  const float* g_ebn2  = (const float*)d_in[7];
  const float* be_ebn2 = (const float*)d_in[8];
  const float* w_c1    = (const float*)d_in[9];
  const float* b_c1    = (const float*)d_in[10];
  const float* w_c2    = (const float*)d_in[11];
  const float* b_c2    = (const float*)d_in[12];
  const float* g_bn1   = (const float*)d_in[13];
  const float* be_bn1  = (const float*)d_in[14];
  const float* g_bn2   = (const float*)d_in[15];
  const float* be_bn2  = (const float*)d_in[16];
  const float* w_1k    = (const float*)d_in[17];
  const float* b_1k    = (const float*)d_in[18];
  float* outp = (float*)d_out;

  char* ws = (char*)d_ws;
  float* B  = (float*)ws;                                   // 268435456 B
  float* X1 = (float*)(ws + 268435456);                     // 33554432 B
  float* X2 = (float*)(ws + 268435456 + 33554432);          // 16777216 B
  char*  sb = ws + 268435456 + 33554432 + 16777216;
  double* SP  = (double*)sb;        // 16*65 = 1040
  double* S2  = SP  + 1040;         // 512
  double* SV  = S2  + 512;          // 512
  double* SB1 = SV  + 512;          // 512
  double* SB2 = SB1 + 512;          // 256
  float*  AB1  = (float*)(SB2 + 256);  // 32
  float*  AB2  = AB1 + 32;             // 32
  float*  ABB1 = AB2 + 32;             // 32
  float*  ABB2 = ABB1 + 32;            // 16
  int*    IDX  = (int*)(ABB2 + 16);    // 48

  const double invM_bn = 1.0/4194304.0;   // N*H*W per channel

  k_zero<<<12,256,0,stream>>>(SP, 2832);
  k_cov<<<dim3(64,16),256,0,stream>>>(x, SP);
  k_fin1<<<1,128,0,stream>>>(SP, w_ext1, b_ext1, g_ebn1, be_ebn1, AB1);
  k_band2<<<dim3(64,16),256,0,stream>>>(x, w_ext1, b_ext1, AB1, w_ext2, b_ext2, B, S2);
  k_fin<<<1,64,0,stream>>>(S2, g_ebn2, be_ebn2, AB2, 16, invM_bn);
  k_varstats<<<dim3(64,16,16),256,0,stream>>>(B, AB2, SV);
  k_topk<<<1,256,0,stream>>>(SV, IDX);
  k_conv1p<<<dim3(256,16),256,0,stream>>>(B, IDX, AB2, w_c1, b_c1, X1);
  k_conv2p<<<dim3(64,16),256,0,stream>>>(X1, w_c2, b_c2, X2);
  k_stats_up4<<<dim3(256,16,16),256,0,stream>>>(X2, SB1);
  k_stats_up2<<<dim3(256,8,16),256,0,stream>>>(X1, SB2);
  k_fin<<<1,64,0,stream>>>(SB1, g_bn1, be_bn1, ABB1, 16, invM_bn);
  k_fin<<<1,64,0,stream>>>(SB2, g_bn2, be_bn2, ABB2, 8, invM_bn);
  k_final<<<dim3(256,16),256,0,stream>>>(X1, X2, ABB1, ABB2, w_1k, b_1k, outp);
}